// Round 5
// baseline (60.649 us; speedup 1.0000x reference)
//
#include <hip/hip_runtime.h>

// Per-channel color-temperature scale: out[b,c,h,w] = in[b,c,h,w] * cm[c]
// cm = {255, 236, 224} / 255, imgs (64,3,512,512) fp32 NCHW.
//
// R5: R4's winning data path (cacheable load -> L3-resident input across
// graph replays; non-temporal store -> write stream bypasses L3) + 2 float4
// per thread for doubled per-wave memory-level parallelism. Two coalesced
// streams per block: [base + t] and [base + t + 256].

typedef float vf4 __attribute__((ext_vector_type(4)));

__global__ __launch_bounds__(256) void RandomAdjustTemp_kernel(
    const vf4* __restrict__ in, vf4* __restrict__ out, int n4) {
    const float cm1 = 236.0f / 255.0f;
    const float cm2 = 224.0f / 255.0f;
    const int i0 = blockIdx.x * 512 + threadIdx.x;   // 512 float4 per block
    const int i1 = i0 + 256;

    // channel of a float4-index i: (i >> 16) % 3   (65536 float4 per plane)
    if (i0 < n4) {
        const int ch0 = (i0 >> 16) % 3;
        const float m0 = (ch0 == 0) ? 1.0f : (ch0 == 1 ? cm1 : cm2);
        vf4 v0 = in[i0];
        v0 *= m0;
        __builtin_nontemporal_store(v0, &out[i0]);
    }
    if (i1 < n4) {
        const int ch1 = (i1 >> 16) % 3;
        const float m1 = (ch1 == 0) ? 1.0f : (ch1 == 1 ? cm1 : cm2);
        vf4 v1 = in[i1];
        v1 *= m1;
        __builtin_nontemporal_store(v1, &out[i1]);
    }
}

extern "C" void kernel_launch(void* const* d_in, const int* in_sizes, int n_in,
                              void* d_out, int out_size, void* d_ws, size_t ws_size,
                              hipStream_t stream) {
    const vf4* in = (const vf4*)d_in[0];
    vf4* out = (vf4*)d_out;
    const int n = in_sizes[0];          // 50,331,648 (divisible by 4)
    const int n4 = n >> 2;              // 12,582,912 float4s
    const int block = 256;
    const int per_block = block * 2;    // 2 float4 per thread
    const int grid = (n4 + per_block - 1) / per_block;  // 24,576 blocks
    RandomAdjustTemp_kernel<<<grid, block, 0, stream>>>(in, out, n4);
}